// Round 18
// baseline (475.142 us; speedup 1.0000x reference)
//
#include <hip/hip_runtime.h>
#include <stdint.h>

typedef unsigned short u16;
typedef unsigned short u16x4 __attribute__((ext_vector_type(4)));
typedef short bf16x8 __attribute__((ext_vector_type(8)));
typedef float f32x4 __attribute__((ext_vector_type(4)));

#define CDIM 256
#define MSZ 65536

// ---------------- ws layout (bytes) ----------------
constexpr size_t O_XB   = 0;                       // 64MB x bf16 NHWC
constexpr size_t O_AT   = 67108864;                // fp32 B=A^T A (dead after powerB)
constexpr size_t O_PQH  = 67108864;                // alias B
constexpr size_t O_PQL  = O_PQH + 524288;
constexpr size_t O_SVAL = 68419584;
constexpr size_t O_W0   = 68419840;                // h,l,th,tl each 655360 B
constexpr size_t O_W1   = 71041280;
constexpr size_t O_PH   = 71041280;                // alias W1 (dead after bjorck)
constexpr size_t O_PL   = O_PH + 524288;
constexpr size_t O_QTH  = O_PL + 524288;
constexpr size_t O_QTL  = O_QTH + 524288;
constexpr size_t O_TH   = 73662720;
constexpr size_t O_TL   = O_TH + 655360;
constexpr size_t O_RTH  = 74973440;
constexpr size_t O_RTL  = O_RTH + 1179648;
constexpr size_t O_WBQ  = O_RTL + 1179648;         // 72 stages x 16KB = 1152KB

__device__ __forceinline__ u16 f2bf(float f) {
  union { float f; uint32_t u; } a; a.f = f;
  uint32_t u = a.u;
  uint32_t r = u + 0x7FFFu + ((u >> 16) & 1u);
  return (u16)(r >> 16);
}
__device__ __forceinline__ float bf2f(u16 u) {
  union { uint32_t u; float f; } a; a.u = ((uint32_t)u) << 16; return a.f;
}
__device__ __forceinline__ void split_st(u16* hi, u16* lo, float v) {
  u16 h = f2bf(v);
  *hi = h;
  *lo = f2bf(v - bf2f(h));
}
// async global->LDS, 16B per lane; l must be wave-uniform (dest = l + lane*16)
__device__ __forceinline__ void gl16(const void* g, void* l) {
  __builtin_amdgcn_global_load_lds(
      (const __attribute__((address_space(1))) void*)g,
      (__attribute__((address_space(3))) void*)l, 16, 0, 0);
}

// convert block body: x NCHW f32 -> xb NHWC bf16, one 32c x 32w tile
__device__ __forceinline__ void cvt_block(const float* __restrict__ x,
                                          u16* __restrict__ xb, int b, char* smem) {
  float (*t)[33] = (float(*)[33])smem;
  int ctile = b & 7, wtile = (b >> 3) & 1, h = (b >> 4) & 63, n = b >> 10;
  int c0 = ctile * 32, w0 = wtile * 32;
  int tid = threadIdx.x;
  #pragma unroll
  for (int p = 0; p < 4; p++) {
    int e = tid + p * 256; int cc = e >> 5, ww = e & 31;
    t[cc][ww] = x[(((size_t)n * 256 + c0 + cc) * 64 + h) * 64 + w0 + ww];
  }
  __syncthreads();
  {
    int ww = tid >> 3, c4 = (tid & 7) * 4;
    u16x4 v;
    #pragma unroll
    for (int j = 0; j < 4; ++j) v[j] = f2bf(t[c4 + j][ww]);
    *(u16x4*)&xb[(((size_t)n * 64 + h) * 64 + w0 + ww) * 256 + c0 + c4] = v;
  }
}

// ---------------- B = A^T A (fp32 VALU GEMM) ----------------
__global__ void wtwA_k(const float* __restrict__ W, float* __restrict__ T) {
  int m = blockIdx.y;
  int i0 = (blockIdx.x >> 3) * 32, j0 = (blockIdx.x & 7) * 32;
  const float* A = W + (size_t)m * MSZ;
  __shared__ float As[32][33], Bs[32][33];
  int tid = threadIdx.x, tx = tid & 15, ty = tid >> 4;
  float a00 = 0, a01 = 0, a10 = 0, a11 = 0;
  for (int kc = 0; kc < CDIM; kc += 32) {
    __syncthreads();
    for (int p = 0; p < 4; p++) {
      int e = tid + p * 256; int kk = e >> 5, cc = e & 31;
      As[kk][cc] = A[(kc + kk) * CDIM + i0 + cc];
      Bs[kk][cc] = A[(kc + kk) * CDIM + j0 + cc];
    }
    __syncthreads();
    #pragma unroll
    for (int kk = 0; kk < 32; kk++) {
      float av0 = As[kk][ty], av1 = As[kk][ty + 16];
      float bv0 = Bs[kk][tx], bv1 = Bs[kk][tx + 16];
      a00 += av0 * bv0; a01 += av0 * bv1; a10 += av1 * bv0; a11 += av1 * bv1;
    }
  }
  float* Tm = T + (size_t)m * MSZ;
  Tm[(i0 + ty) * CDIM + j0 + tx] = a00;
  Tm[(i0 + ty) * CDIM + j0 + tx + 16] = a01;
  Tm[(i0 + ty + 16) * CDIM + j0 + tx] = a10;
  Tm[(i0 + ty + 16) * CDIM + j0 + tx + 16] = a11;
}

// ---------------- power iteration via B = A^T A ----------------
__global__ __launch_bounds__(1024) void powerB_k(const float* __restrict__ A,
                                                 const float* __restrict__ B,
                                                 const float* __restrict__ u0,
                                                 float* __restrict__ sval) {
  int m = blockIdx.x;
  int tid = threadIdx.x;
  int t = tid & 255, s = tid >> 8;          // col t, row-slice s
  __shared__ float v[256], part[4][257];
  const float* Am = A + (size_t)m * MSZ;
  const float* Bm = B + (size_t)m * MSZ;
  float a = 0.f;
  #pragma unroll 16
  for (int i = 0; i < 64; ++i) a += Am[(s * 64 + i) * 256 + t] * u0[m * 256 + s * 64 + i];
  part[s][t] = a;
  __syncthreads();
  if (s == 0) v[t] = part[0][t] + part[1][t] + part[2][t] + part[3][t];
  __syncthreads();
  for (int it = 0; it < 9; ++it) {
    float b = 0.f;
    #pragma unroll 16
    for (int j = 0; j < 64; ++j) b += Bm[(s * 64 + j) * 256 + t] * v[s * 64 + j];
    part[s][t] = b;
    __syncthreads();
    if (s == 0) v[t] = part[0][t] + part[1][t] + part[2][t] + part[3][t];
    __syncthreads();
  }
  float b = 0.f;
  #pragma unroll 16
  for (int j = 0; j < 64; ++j) b += Bm[(s * 64 + j) * 256 + t] * v[s * 64 + j];
  part[s][t] = b;
  __syncthreads();
  if (s == 0) {
    float w = part[0][t] + part[1][t] + part[2][t] + part[3][t];
    float vv = v[t];
    float d1 = vv * w, d2 = vv * vv;
    for (int off = 32; off; off >>= 1) {
      d1 += __shfl_down(d1, off);
      d2 += __shfl_down(d2, off);
    }
    if ((t & 63) == 0) { part[1][t >> 6] = d1; part[2][t >> 6] = d2; }
  }
  __syncthreads();
  if (tid == 0) {
    float num = part[1][0] + part[1][1] + part[1][2] + part[1][3];
    float den = part[2][0] + part[2][1] + part[2][2] + part[2][3];
    sval[m] = sqrtf(num / den);
  }
}

// ---------------- scale + transpose + hi/lo split in one pass ----------------
__global__ void scaleT_k(const float* __restrict__ param, const float* __restrict__ sval,
                         u16* __restrict__ Wh, u16* __restrict__ Wl,
                         u16* __restrict__ Wth, u16* __restrict__ Wtl) {
  __shared__ float tl[32][33];
  int m = blockIdx.y;
  int i0 = (blockIdx.x >> 3) * 32, j0 = (blockIdx.x & 7) * 32;
  int tid = threadIdx.x;
  float inv = 1.0f / sval[m];
  const float* Am = param + (size_t)m * MSZ;
  size_t mo = (size_t)m * MSZ;
  for (int p = 0; p < 4; ++p) {
    int e = tid + p * 256; int ii = e >> 5, jj = e & 31;
    float v = Am[(i0 + ii) * 256 + j0 + jj] * inv;
    tl[ii][jj] = v;
    size_t idx = mo + (size_t)(i0 + ii) * 256 + j0 + jj;
    split_st(&Wh[idx], &Wl[idx], v);
  }
  __syncthreads();
  for (int p = 0; p < 4; ++p) {
    int e = tid + p * 256; int jj = e >> 5, ii = e & 31;
    float v = tl[ii][jj];
    size_t idxT = mo + (size_t)(j0 + jj) * 256 + i0 + ii;
    split_st(&Wth[idxT], &Wtl[idxT], v);
  }
}

// ---------------- hi/lo-split MFMA 32x32-tile GEMM: C += A·B^T ----------------
__device__ __forceinline__ void gemm32_acc(
    const u16* __restrict__ Ah, const u16* __restrict__ Al, int i0,
    const u16* __restrict__ Bh, const u16* __restrict__ Bl, int j0,
    int K, f32x4* acc, char* smem, int tid)
{
  int lane = tid & 63, wave = tid >> 6;
  int qm = wave >> 1, qn = wave & 1;
  int ra = qm * 16 + (lane & 15);
  int rb = qn * 16 + (lane & 15);
  int kb = (lane >> 4) * 16;
  for (int kc = 0; kc < K; kc += 128) {
    __syncthreads();
    #pragma unroll
    for (int p = 0; p < 8; ++p) {
      int e = tid + p * 256;
      int bufi = e >> 9;                 // 0:Ah 1:Al 2:Bh 3:Bl
      int r = (e >> 4) & 31;
      int cb = (e & 15) * 16;
      const u16* srcm = (bufi == 0) ? Ah : (bufi == 1) ? Al : (bufi == 2) ? Bh : Bl;
      int r0 = (bufi < 2) ? i0 : j0;
      const char* src = (const char*)srcm + ((size_t)(r0 + r) * 256 + kc) * 2 + cb;
      *(uint4*)(smem + bufi * 8192 + r * 256 + (cb ^ ((r & 7) << 4))) = *(const uint4*)src;
    }
    __syncthreads();
    #pragma unroll
    for (int ks = 0; ks < 4; ++ks) {
      int kbyte = ks * 64 + kb;
      int oa = ra * 256 + (kbyte ^ ((ra & 7) << 4));
      int ob = rb * 256 + (kbyte ^ ((rb & 7) << 4));
      bf16x8 ah = *(const bf16x8*)(smem + oa);
      bf16x8 al = *(const bf16x8*)(smem + 8192 + oa);
      bf16x8 bh = *(const bf16x8*)(smem + 16384 + ob);
      bf16x8 bl = *(const bf16x8*)(smem + 24576 + ob);
      *acc = __builtin_amdgcn_mfma_f32_16x16x32_bf16(ah, bh, *acc, 0, 0, 0);
      *acc = __builtin_amdgcn_mfma_f32_16x16x32_bf16(ah, bl, *acc, 0, 0, 0);
      *acc = __builtin_amdgcn_mfma_f32_16x16x32_bf16(al, bh, *acc, 0, 0, 0);
    }
  }
}

#define GEMM_IDX \
  int tid = threadIdx.x; \
  int lane = tid & 63, wave = tid >> 6, qm = wave >> 1, qn = wave & 1; \
  int orow = qm * 16 + ((lane >> 4) << 2); \
  int ocol = qn * 16 + (lane & 15); \
  int i0 = (blockIdx.x >> 3) * 32, j0 = (blockIdx.x & 7) * 32; \
  __shared__ char smem[32768];

// ---------------- Bjorck step 1: T = W^T W (+ piggybacked convert blocks) ----------------
__global__ __launch_bounds__(256) void bjorck_t_k(
    const u16* __restrict__ Wth, const u16* __restrict__ Wtl,
    u16* __restrict__ Th, u16* __restrict__ Tl,
    const float* __restrict__ x, u16* __restrict__ xb, int cvt_base) {
  __shared__ char smem[32768];
  int bx = blockIdx.x;
  if (bx >= 320) {
    int b = cvt_base + bx - 320;
    if (b < 32768) cvt_block(x, xb, b, smem);
    return;
  }
  int tid = threadIdx.x;
  int lane = tid & 63, wave = tid >> 6, qm = wave >> 1, qn = wave & 1;
  int orow = qm * 16 + ((lane >> 4) << 2);
  int ocol = qn * 16 + (lane & 15);
  int i0 = ((bx & 63) >> 3) * 32, j0 = (bx & 7) * 32;
  size_t mo = (size_t)(bx >> 6) * MSZ;
  f32x4 acc = {};
  gemm32_acc(Wth + mo, Wtl + mo, i0, Wth + mo, Wtl + mo, j0, 256, &acc, smem, tid);
  #pragma unroll
  for (int v = 0; v < 4; ++v) {
    size_t idx = mo + (size_t)(i0 + orow + v) * 256 + (j0 + ocol);
    split_st(&Th[idx], &Tl[idx], acc[v]);
  }
}

// ---------------- Bjorck step 2: Wn = 1.5W - 0.5 W·T (+ Wn^T, + convert blocks) ----------------
__global__ __launch_bounds__(256) void bjorck_u_k(
    const u16* __restrict__ Wh, const u16* __restrict__ Wl,
    const u16* __restrict__ Th, const u16* __restrict__ Tl,
    u16* __restrict__ nWh, u16* __restrict__ nWl,
    u16* __restrict__ nWth, u16* __restrict__ nWtl,
    const float* __restrict__ x, u16* __restrict__ xb, int cvt_base) {
  __shared__ char smem[32768];
  int bx = blockIdx.x;
  if (bx >= 320) {
    int b = cvt_base + bx - 320;
    if (b < 32768) cvt_block(x, xb, b, smem);
    return;
  }
  int tid = threadIdx.x;
  int lane = tid & 63, wave = tid >> 6, qm = wave >> 1, qn = wave & 1;
  int orow = qm * 16 + ((lane >> 4) << 2);
  int ocol = qn * 16 + (lane & 15);
  int i0 = ((bx & 63) >> 3) * 32, j0 = (bx & 7) * 32;
  size_t mo = (size_t)(bx >> 6) * MSZ;
  f32x4 acc = {};
  gemm32_acc(Wh + mo, Wl + mo, i0, Th + mo, Tl + mo, j0, 256, &acc, smem, tid);
  #pragma unroll
  for (int v = 0; v < 4; ++v) {
    int r = i0 + orow + v, c = j0 + ocol;
    size_t idx = mo + (size_t)r * 256 + c;
    float wv = bf2f(Wh[idx]) + bf2f(Wl[idx]);
    float nv = 1.5f * wv - 0.5f * acc[v];
    split_st(&nWh[idx], &nWl[idx], nv);
    size_t idxT = mo + (size_t)c * 256 + r;
    split_st(&nWth[idxT], &nWtl[idxT], nv);
  }
}

// ---------------- PQ[t] = masked(O)·masked(O)^T (K=128) ----------------
__global__ __launch_bounds__(256) void pq_k(
    const u16* __restrict__ Wh, const u16* __restrict__ Wl,
    u16* __restrict__ PQh, u16* __restrict__ PQl) {
  GEMM_IDX
  int m4 = blockIdx.y;
  const u16* Oh = Wh + (size_t)(1 + m4) * MSZ;
  const u16* Ol = Wl + (size_t)(1 + m4) * MSZ;
  f32x4 acc = {};
  gemm32_acc(Oh, Ol, i0, Oh, Ol, j0, 128, &acc, smem, tid);
  #pragma unroll
  for (int v = 0; v < 4; ++v) {
    size_t idx = (size_t)m4 * MSZ + (size_t)(i0 + orow + v) * 256 + (j0 + ocol);
    split_st(&PQh[idx], &PQl[idx], acc[v]);
  }
}

// ---------------- fused: C1 = PQ0·PQ1, C2t = PQ3·PQ2, then block-orth members ----------------
__global__ __launch_bounds__(256) void c12b_k(
    const u16* __restrict__ PQh, const u16* __restrict__ PQl,
    u16* __restrict__ Ph, u16* __restrict__ Pl,
    u16* __restrict__ QTh, u16* __restrict__ QTl) {
  GEMM_IDX
  f32x4 a1 = {}, a2t = {};
  gemm32_acc(PQh, PQl, i0, PQh + MSZ, PQl + MSZ, j0, 256, &a1, smem, tid);
  gemm32_acc(PQh + 3 * MSZ, PQl + 3 * MSZ, i0, PQh + 2 * MSZ, PQl + 2 * MSZ, j0,
             256, &a2t, smem, tid);
  #pragma unroll
  for (int v = 0; v < 4; ++v) {
    int row = i0 + orow + v, col = j0 + ocol;
    size_t g = (size_t)row * 256 + col;
    float I = (row == col) ? 1.f : 0.f;
    float p0 = bf2f(PQh[g]) + bf2f(PQl[g]);
    float p1 = bf2f(PQh[MSZ + g]) + bf2f(PQl[MSZ + g]);
    float c1 = a1[v];
    split_st(&Ph[g],           &Pl[g],           c1);
    split_st(&Ph[MSZ + g],     &Pl[MSZ + g],     p0 - c1);
    split_st(&Ph[2*MSZ + g],   &Pl[2*MSZ + g],   p1 - c1);
    split_st(&Ph[3*MSZ + g],   &Pl[3*MSZ + g],   I - p0 - p1 + c1);
    float q0 = bf2f(PQh[2*MSZ + g]) + bf2f(PQl[2*MSZ + g]);
    float q1 = bf2f(PQh[3*MSZ + g]) + bf2f(PQl[3*MSZ + g]);
    float c2t = a2t[v];
    split_st(&QTh[g],          &QTl[g],          c2t);
    split_st(&QTh[MSZ + g],    &QTl[MSZ + g],    q0 - c2t);
    split_st(&QTh[2*MSZ + g],  &QTl[2*MSZ + g],  q1 - c2t);
    split_st(&QTh[3*MSZ + g],  &QTl[3*MSZ + g],  I - q0 - q1 + c2t);
  }
}

// ---------------- matrix_conv: R[ij] = sum_t P[tp]·Q[tq]; store R^T ----------------
__global__ __launch_bounds__(256) void mconv_k(
    const u16* __restrict__ Ph, const u16* __restrict__ Pl,
    const u16* __restrict__ QTh, const u16* __restrict__ QTl,
    u16* __restrict__ RTh, u16* __restrict__ RTl) {
  GEMM_IDX
  int ij = blockIdx.y;
  const int toff[10] = {0, 1, 3, 4, 6, 10, 12, 13, 15, 16};
  const int tp[16] = {0, 0, 1, 1, 0, 2, 0, 1, 2, 3, 1, 3, 2, 2, 3, 3};
  const int tq[16] = {0, 1, 0, 1, 2, 0, 3, 2, 1, 0, 3, 1, 2, 3, 2, 3};
  f32x4 acc = {};
  for (int t = toff[ij]; t < toff[ij + 1]; ++t) {
    gemm32_acc(Ph + (size_t)tp[t] * MSZ, Pl + (size_t)tp[t] * MSZ, i0,
               QTh + (size_t)tq[t] * MSZ, QTl + (size_t)tq[t] * MSZ, j0, 256, &acc, smem, tid);
  }
  #pragma unroll
  for (int v = 0; v < 4; ++v) {
    int r = i0 + orow + v, c = j0 + ocol;
    size_t idxT = (size_t)ij * MSZ + (size_t)c * 256 + r;  // R^T
    split_st(&RTh[idxT], &RTl[idxT], acc[v]);
  }
}

// ---------------- Wb: stage-major, per-stage [cout][kslice] for coalesced
// direct-from-global B-fragments. stage g = ct*18 + ij*2 + ks, 16KB each.
// u16 index = g*8192 + cout*32 + q*8 + e, where cin = ct*64+ks*32+q*8+e.
__global__ __launch_bounds__(256) void final_k(
    const u16* __restrict__ Hh, const u16* __restrict__ Hl,
    const u16* __restrict__ RTh, const u16* __restrict__ RTl,
    u16* __restrict__ WBQ) {
  GEMM_IDX
  int ij = blockIdx.y;
  f32x4 acc = {};
  gemm32_acc(Hh, Hl, i0, RTh + (size_t)ij * MSZ, RTl + (size_t)ij * MSZ, j0,
             256, &acc, smem, tid);
  #pragma unroll
  for (int v = 0; v < 4; ++v) {
    int r = i0 + orow + v, c = j0 + ocol;   // r = cin, c = cout
    int ct = r >> 6, ks = (r >> 5) & 1, qq = (r >> 3) & 3, e = r & 7;
    int g = ct * 18 + ij * 2 + ks;
    WBQ[(size_t)g * 8192 + (size_t)c * 32 + qq * 8 + e] = f2bf(acc[v]);
  }
}

// ---------------- conv: implicit GEMM, MFMA bf16 ----------------
// grid 1024 (XCD-swizzled), 512 thr (8 waves, 2M x 4N). block = 2h x 64w x 256c.
// LDS 64KB = double-buffered X only (gload_lds, pre-swizzled source).
// W read DIRECTLY from global (stage-major WBQ; wave reads 1KB contiguous,
// L1/L2-resident) -> no W LDS traffic, 1 barrier per cin-tile (4 total).
__global__ __launch_bounds__(512, 2) void conv_k(
    const u16* __restrict__ xb, const u16* __restrict__ Wb,
    const float* __restrict__ bias, float* __restrict__ out) {
  int braw = blockIdx.x;
  int L = (braw & 7) * 128 + (braw >> 3);   // bijective XCD swizzle (1024 % 8 == 0)
  int h2 = L & 31, n = L >> 5;
  int h0 = h2 * 2;
  int tid = threadIdx.x;
  int lane = tid & 63, wave = tid >> 6;
  int wm = wave >> 2, wn = wave & 3;        // 2 M-halves x 4 N-quarters
  int fr = lane & 15, q = lane >> 4;

  __shared__ char smem[65536];              // [buf2][r4][w64][128B cin] swizzled

  f32x4 acc[4][4] = {};

  auto issueX = [&](int ct, int buf) {
    #pragma unroll
    for (int i = 0; i < 4; ++i) {
      int d = (wave * 4 + i) * 64 + lane;   // chunk 0..2047
      int cb = (d & 7) * 16;
      int w = (d >> 3) & 63;
      int r = d >> 9;                       // 0..3 = rows h0-1..h0+2
      int hs = (h0 - 1 + r) & 63;
      const char* src = (const char*)xb + (((size_t)(n * 64 + hs) * 64 + w) << 9)
                        + ct * 128 + (cb ^ ((w & 7) << 4));
      gl16(src, smem + buf * 32768 + (wave * 4 + i) * 1024);
    }
  };

  issueX(0, 0);
  __syncthreads();                          // X0 landed

  // per-lane W base: cout row (wn*64 + fr), k-slice q
  const char* wlane = (const char*)Wb + (size_t)(wn * 64 + fr) * 64 + q * 16;

  for (int ct = 0; ct < 4; ++ct) {
    if (ct < 3) issueX(ct + 1, (ct + 1) & 1);   // flies across all 18 stages
    const char* sX = smem + (ct & 1) * 32768;
    for (int r18 = 0; r18 < 18; ++r18) {
      int g = ct * 18 + r18;
      int tap = r18 >> 1, ks = r18 & 1;
      int kh = tap % 3, kw = tap / 3;       // tap == ij == kw*3+kh
      __builtin_amdgcn_s_setprio(1);
      {
        bf16x8 af[4], bfr[4];
        const char* wg = wlane + (size_t)g * 16384;
        #pragma unroll
        for (int fn = 0; fn < 4; ++fn)
          bfr[fn] = *(const bf16x8*)(wg + fn * 1024);   // fn*16 couts * 64B
        int kb2 = ks * 64 + q * 16;
        #pragma unroll
        for (int fm = 0; fm < 4; ++fm) {
          int wsrc = (fm * 16 + fr + kw + 63) & 63;
          af[fm] = *(const bf16x8*)(sX + ((wm + kh) * 64 + wsrc) * 128 + (kb2 ^ ((wsrc & 7) << 4)));
        }
        #pragma unroll
        for (int fm = 0; fm < 4; ++fm)
          #pragma unroll
          for (int fn = 0; fn < 4; ++fn)
            acc[fm][fn] = __builtin_amdgcn_mfma_f32_16x16x32_bf16(af[fm], bfr[fn], acc[fm][fn], 0, 0, 0);
      }
      __builtin_amdgcn_s_setprio(0);
    }
    __syncthreads();   // all waves done reading sX(ct); X(ct+1) landed (vmcnt drained)
  }

  // epilogue: 2 rounds x 128 couts through LDS -> full 256B-row stores
  float* sF = (float*)smem;                 // [cl128][h2][64w f32] swizzled, 64KB
  #pragma unroll
  for (int r = 0; r < 2; ++r) {
    if ((wn >> 1) == r) {
      #pragma unroll
      for (int fn = 0; fn < 4; ++fn) {
        int cl = (wn & 1) * 64 + fn * 16 + fr;       // 0..127
        float bv = bias[r * 128 + cl];
        #pragma unroll
        for (int fm = 0; fm < 4; ++fm) {
          f32x4 v = acc[fm][fn];
          v[0] += bv; v[1] += bv; v[2] += bv; v[3] += bv;
          *(f32x4*)((char*)sF + cl * 512 + wm * 256 +
                    (((unsigned)(fm * 64 + q * 16)) ^ ((unsigned)(cl & 7) << 4))) = v;
        }
      }
    }
    __syncthreads();
    #pragma unroll
    for (int p = 0; p < 8; ++p) {
      int e = tid + p * 512;                // 0..4095 f32x4 units
      int w4 = e & 15, hloc = (e >> 4) & 1, cl = e >> 5;   // cl 0..127
      f32x4 val = *(const f32x4*)((const char*)sF + cl * 512 + hloc * 256 +
                                  (((unsigned)(w4 * 16)) ^ ((unsigned)(cl & 7) << 4)));
      *(f32x4*)(out + (((size_t)n * 256 + r * 128 + cl) * 64 + (h0 + hloc)) * 64 + w4 * 4) = val;
    }
    if (r == 0) __syncthreads();            // WAR before round-1 LDS writes
  }
}

extern "C" void kernel_launch(void* const* d_in, const int* in_sizes, int n_in,
                              void* d_out, int out_size, void* d_ws, size_t ws_size,
                              hipStream_t stream) {
  const float* x = (const float*)d_in[0];
  const float* param = (const float*)d_in[1];
  const float* u0 = (const float*)d_in[2];
  const float* bias = (const float*)d_in[3];
  float* out = (float*)d_out;
  char* ws = (char*)d_ws;
  (void)in_sizes; (void)n_in; (void)out_size; (void)ws_size;

  float* B = (float*)(ws + O_AT);
  float* sval = (float*)(ws + O_SVAL);
  u16* xb = (u16*)(ws + O_XB);
  u16* W0h  = (u16*)(ws + O_W0);   u16* W0l  = W0h + 327680;
  u16* W0th = W0l + 327680;        u16* W0tl = W0th + 327680;
  u16* W1h  = (u16*)(ws + O_W1);   u16* W1l  = W1h + 327680;
  u16* W1th = W1l + 327680;        u16* W1tl = W1th + 327680;
  u16* Th = (u16*)(ws + O_TH);     u16* Tl = (u16*)(ws + O_TL);
  u16* PQh = (u16*)(ws + O_PQH);   u16* PQl = (u16*)(ws + O_PQL);
  u16* Ph = (u16*)(ws + O_PH);     u16* Pl = (u16*)(ws + O_PL);
  u16* QTh = (u16*)(ws + O_QTH);   u16* QTl = (u16*)(ws + O_QTL);
  u16* RTh = (u16*)(ws + O_RTH);   u16* RTl = (u16*)(ws + O_RTL);
  u16* WBQ = (u16*)(ws + O_WBQ);

  wtwA_k<<<dim3(64, 5), 256, 0, stream>>>(param, B);
  powerB_k<<<5, 1024, 0, stream>>>(param, B, u0, sval);
  scaleT_k<<<dim3(64, 5), 256, 0, stream>>>(param, sval, W0h, W0l, W0th, W0tl);

  u16 *cWh = W0h, *cWl = W0l, *cWth = W0th, *cWtl = W0tl;
  u16 *nWh = W1h, *nWl = W1l, *nWth = W1th, *nWtl = W1tl;
  for (int it = 0; it < 20; ++it) {
    bjorck_t_k<<<1140, 256, 0, stream>>>(cWth, cWtl, Th, Tl,
                                         x, xb, (2 * it) * 820);
    bjorck_u_k<<<1140, 256, 0, stream>>>(cWh, cWl, Th, Tl, nWh, nWl, nWth, nWtl,
                                         x, xb, (2 * it + 1) * 820);
    u16* t0;
    t0 = cWh; cWh = nWh; nWh = t0;
    t0 = cWl; cWl = nWl; nWl = t0;
    t0 = cWth; cWth = nWth; nWth = t0;
    t0 = cWtl; cWtl = nWtl; nWtl = t0;
  }
  // after 20 swaps cur == W0; W1 region is dead -> P/QT alias is safe

  pq_k<<<dim3(64, 4), 256, 0, stream>>>(cWh, cWl, PQh, PQl);
  c12b_k<<<64, 256, 0, stream>>>(PQh, PQl, Ph, Pl, QTh, QTl);
  mconv_k<<<dim3(64, 9), 256, 0, stream>>>(Ph, Pl, QTh, QTl, RTh, RTl);
  final_k<<<dim3(64, 9), 256, 0, stream>>>(cWh, cWl, RTh, RTl, WBQ);

  conv_k<<<1024, 512, 0, stream>>>(xb, WBQ, bias, out);
}

// Round 19
// 444.685 us; speedup vs baseline: 1.0685x; 1.0685x over previous
//
#include <hip/hip_runtime.h>
#include <stdint.h>

typedef unsigned short u16;
typedef unsigned short u16x4 __attribute__((ext_vector_type(4)));
typedef short bf16x8 __attribute__((ext_vector_type(8)));
typedef float f32x4 __attribute__((ext_vector_type(4)));

#define CDIM 256
#define MSZ 65536

// ---------------- ws layout (bytes) ----------------
constexpr size_t O_XB   = 0;                       // 64MB x bf16 NHWC
constexpr size_t O_AT   = 67108864;                // fp32 B=A^T A (dead after powerB)
constexpr size_t O_PQH  = 67108864;                // alias B
constexpr size_t O_PQL  = O_PQH + 524288;
constexpr size_t O_SVAL = 68419584;
constexpr size_t O_W0   = 68419840;                // h,l,th,tl each 655360 B
constexpr size_t O_W1   = 71041280;
constexpr size_t O_PH   = 71041280;                // alias W1 (dead after bjorck)
constexpr size_t O_PL   = O_PH + 524288;
constexpr size_t O_QTH  = O_PL + 524288;
constexpr size_t O_QTL  = O_QTH + 524288;
constexpr size_t O_TH   = 73662720;
constexpr size_t O_TL   = O_TH + 655360;
constexpr size_t O_RTH  = 74973440;
constexpr size_t O_RTL  = O_RTH + 1179648;
constexpr size_t O_WBQ  = O_RTL + 1179648;         // 72 stages x 16KB = 1152KB

__device__ __forceinline__ u16 f2bf(float f) {
  union { float f; uint32_t u; } a; a.f = f;
  uint32_t u = a.u;
  uint32_t r = u + 0x7FFFu + ((u >> 16) & 1u);
  return (u16)(r >> 16);
}
__device__ __forceinline__ float bf2f(u16 u) {
  union { uint32_t u; float f; } a; a.u = ((uint32_t)u) << 16; return a.f;
}
__device__ __forceinline__ void split_st(u16* hi, u16* lo, float v) {
  u16 h = f2bf(v);
  *hi = h;
  *lo = f2bf(v - bf2f(h));
}
// async global->LDS, 16B per lane; l must be wave-uniform (dest = l + lane*16)
__device__ __forceinline__ void gl16(const void* g, void* l) {
  __builtin_amdgcn_global_load_lds(
      (const __attribute__((address_space(1))) void*)g,
      (__attribute__((address_space(3))) void*)l, 16, 0, 0);
}

// convert block body: x NCHW f32 -> xb NHWC bf16, one 32c x 32w tile
__device__ __forceinline__ void cvt_block(const float* __restrict__ x,
                                          u16* __restrict__ xb, int b, char* smem) {
  float (*t)[33] = (float(*)[33])smem;
  int ctile = b & 7, wtile = (b >> 3) & 1, h = (b >> 4) & 63, n = b >> 10;
  int c0 = ctile * 32, w0 = wtile * 32;
  int tid = threadIdx.x;
  #pragma unroll
  for (int p = 0; p < 4; p++) {
    int e = tid + p * 256; int cc = e >> 5, ww = e & 31;
    t[cc][ww] = x[(((size_t)n * 256 + c0 + cc) * 64 + h) * 64 + w0 + ww];
  }
  __syncthreads();
  {
    int ww = tid >> 3, c4 = (tid & 7) * 4;
    u16x4 v;
    #pragma unroll
    for (int j = 0; j < 4; ++j) v[j] = f2bf(t[c4 + j][ww]);
    *(u16x4*)&xb[(((size_t)n * 64 + h) * 64 + w0 + ww) * 256 + c0 + c4] = v;
  }
}

// ---------------- B = A^T A (fp32 VALU GEMM) ----------------
__global__ void wtwA_k(const float* __restrict__ W, float* __restrict__ T) {
  int m = blockIdx.y;
  int i0 = (blockIdx.x >> 3) * 32, j0 = (blockIdx.x & 7) * 32;
  const float* A = W + (size_t)m * MSZ;
  __shared__ float As[32][33], Bs[32][33];
  int tid = threadIdx.x, tx = tid & 15, ty = tid >> 4;
  float a00 = 0, a01 = 0, a10 = 0, a11 = 0;
  for (int kc = 0; kc < CDIM; kc += 32) {
    __syncthreads();
    for (int p = 0; p < 4; p++) {
      int e = tid + p * 256; int kk = e >> 5, cc = e & 31;
      As[kk][cc] = A[(kc + kk) * CDIM + i0 + cc];
      Bs[kk][cc] = A[(kc + kk) * CDIM + j0 + cc];
    }
    __syncthreads();
    #pragma unroll
    for (int kk = 0; kk < 32; kk++) {
      float av0 = As[kk][ty], av1 = As[kk][ty + 16];
      float bv0 = Bs[kk][tx], bv1 = Bs[kk][tx + 16];
      a00 += av0 * bv0; a01 += av0 * bv1; a10 += av1 * bv0; a11 += av1 * bv1;
    }
  }
  float* Tm = T + (size_t)m * MSZ;
  Tm[(i0 + ty) * CDIM + j0 + tx] = a00;
  Tm[(i0 + ty) * CDIM + j0 + tx + 16] = a01;
  Tm[(i0 + ty + 16) * CDIM + j0 + tx] = a10;
  Tm[(i0 + ty + 16) * CDIM + j0 + tx + 16] = a11;
}

// ---------------- power iteration via B = A^T A ----------------
__global__ __launch_bounds__(1024) void powerB_k(const float* __restrict__ A,
                                                 const float* __restrict__ B,
                                                 const float* __restrict__ u0,
                                                 float* __restrict__ sval) {
  int m = blockIdx.x;
  int tid = threadIdx.x;
  int t = tid & 255, s = tid >> 8;          // col t, row-slice s
  __shared__ float v[256], part[4][257];
  const float* Am = A + (size_t)m * MSZ;
  const float* Bm = B + (size_t)m * MSZ;
  float a = 0.f;
  #pragma unroll 16
  for (int i = 0; i < 64; ++i) a += Am[(s * 64 + i) * 256 + t] * u0[m * 256 + s * 64 + i];
  part[s][t] = a;
  __syncthreads();
  if (s == 0) v[t] = part[0][t] + part[1][t] + part[2][t] + part[3][t];
  __syncthreads();
  for (int it = 0; it < 9; ++it) {
    float b = 0.f;
    #pragma unroll 16
    for (int j = 0; j < 64; ++j) b += Bm[(s * 64 + j) * 256 + t] * v[s * 64 + j];
    part[s][t] = b;
    __syncthreads();
    if (s == 0) v[t] = part[0][t] + part[1][t] + part[2][t] + part[3][t];
    __syncthreads();
  }
  float b = 0.f;
  #pragma unroll 16
  for (int j = 0; j < 64; ++j) b += Bm[(s * 64 + j) * 256 + t] * v[s * 64 + j];
  part[s][t] = b;
  __syncthreads();
  if (s == 0) {
    float w = part[0][t] + part[1][t] + part[2][t] + part[3][t];
    float vv = v[t];
    float d1 = vv * w, d2 = vv * vv;
    for (int off = 32; off; off >>= 1) {
      d1 += __shfl_down(d1, off);
      d2 += __shfl_down(d2, off);
    }
    if ((t & 63) == 0) { part[1][t >> 6] = d1; part[2][t >> 6] = d2; }
  }
  __syncthreads();
  if (tid == 0) {
    float num = part[1][0] + part[1][1] + part[1][2] + part[1][3];
    float den = part[2][0] + part[2][1] + part[2][2] + part[2][3];
    sval[m] = sqrtf(num / den);
  }
}

// ---------------- scale + transpose + hi/lo split in one pass ----------------
__global__ void scaleT_k(const float* __restrict__ param, const float* __restrict__ sval,
                         u16* __restrict__ Wh, u16* __restrict__ Wl,
                         u16* __restrict__ Wth, u16* __restrict__ Wtl) {
  __shared__ float tl[32][33];
  int m = blockIdx.y;
  int i0 = (blockIdx.x >> 3) * 32, j0 = (blockIdx.x & 7) * 32;
  int tid = threadIdx.x;
  float inv = 1.0f / sval[m];
  const float* Am = param + (size_t)m * MSZ;
  size_t mo = (size_t)m * MSZ;
  for (int p = 0; p < 4; ++p) {
    int e = tid + p * 256; int ii = e >> 5, jj = e & 31;
    float v = Am[(i0 + ii) * 256 + j0 + jj] * inv;
    tl[ii][jj] = v;
    size_t idx = mo + (size_t)(i0 + ii) * 256 + j0 + jj;
    split_st(&Wh[idx], &Wl[idx], v);
  }
  __syncthreads();
  for (int p = 0; p < 4; ++p) {
    int e = tid + p * 256; int jj = e >> 5, ii = e & 31;
    float v = tl[ii][jj];
    size_t idxT = mo + (size_t)(j0 + jj) * 256 + i0 + ii;
    split_st(&Wth[idxT], &Wtl[idxT], v);
  }
}

// ---------------- hi/lo-split MFMA 32x32-tile GEMM: C += A·B^T ----------------
__device__ __forceinline__ void gemm32_acc(
    const u16* __restrict__ Ah, const u16* __restrict__ Al, int i0,
    const u16* __restrict__ Bh, const u16* __restrict__ Bl, int j0,
    int K, f32x4* acc, char* smem, int tid)
{
  int lane = tid & 63, wave = tid >> 6;
  int qm = wave >> 1, qn = wave & 1;
  int ra = qm * 16 + (lane & 15);
  int rb = qn * 16 + (lane & 15);
  int kb = (lane >> 4) * 16;
  for (int kc = 0; kc < K; kc += 128) {
    __syncthreads();
    #pragma unroll
    for (int p = 0; p < 8; ++p) {
      int e = tid + p * 256;
      int bufi = e >> 9;                 // 0:Ah 1:Al 2:Bh 3:Bl
      int r = (e >> 4) & 31;
      int cb = (e & 15) * 16;
      const u16* srcm = (bufi == 0) ? Ah : (bufi == 1) ? Al : (bufi == 2) ? Bh : Bl;
      int r0 = (bufi < 2) ? i0 : j0;
      const char* src = (const char*)srcm + ((size_t)(r0 + r) * 256 + kc) * 2 + cb;
      *(uint4*)(smem + bufi * 8192 + r * 256 + (cb ^ ((r & 7) << 4))) = *(const uint4*)src;
    }
    __syncthreads();
    #pragma unroll
    for (int ks = 0; ks < 4; ++ks) {
      int kbyte = ks * 64 + kb;
      int oa = ra * 256 + (kbyte ^ ((ra & 7) << 4));
      int ob = rb * 256 + (kbyte ^ ((rb & 7) << 4));
      bf16x8 ah = *(const bf16x8*)(smem + oa);
      bf16x8 al = *(const bf16x8*)(smem + 8192 + oa);
      bf16x8 bh = *(const bf16x8*)(smem + 16384 + ob);
      bf16x8 bl = *(const bf16x8*)(smem + 24576 + ob);
      *acc = __builtin_amdgcn_mfma_f32_16x16x32_bf16(ah, bh, *acc, 0, 0, 0);
      *acc = __builtin_amdgcn_mfma_f32_16x16x32_bf16(ah, bl, *acc, 0, 0, 0);
      *acc = __builtin_amdgcn_mfma_f32_16x16x32_bf16(al, bh, *acc, 0, 0, 0);
    }
  }
}

#define GEMM_IDX \
  int tid = threadIdx.x; \
  int lane = tid & 63, wave = tid >> 6, qm = wave >> 1, qn = wave & 1; \
  int orow = qm * 16 + ((lane >> 4) << 2); \
  int ocol = qn * 16 + (lane & 15); \
  int i0 = (blockIdx.x >> 3) * 32, j0 = (blockIdx.x & 7) * 32; \
  __shared__ char smem[32768];

// ---------------- Bjorck step 1: T = W^T W (+ piggybacked convert blocks) ----------------
__global__ __launch_bounds__(256) void bjorck_t_k(
    const u16* __restrict__ Wth, const u16* __restrict__ Wtl,
    u16* __restrict__ Th, u16* __restrict__ Tl,
    const float* __restrict__ x, u16* __restrict__ xb, int cvt_base) {
  __shared__ char smem[32768];
  int bx = blockIdx.x;
  if (bx >= 320) {
    int b = cvt_base + bx - 320;
    if (b < 32768) cvt_block(x, xb, b, smem);
    return;
  }
  int tid = threadIdx.x;
  int lane = tid & 63, wave = tid >> 6, qm = wave >> 1, qn = wave & 1;
  int orow = qm * 16 + ((lane >> 4) << 2);
  int ocol = qn * 16 + (lane & 15);
  int i0 = ((bx & 63) >> 3) * 32, j0 = (bx & 7) * 32;
  size_t mo = (size_t)(bx >> 6) * MSZ;
  f32x4 acc = {};
  gemm32_acc(Wth + mo, Wtl + mo, i0, Wth + mo, Wtl + mo, j0, 256, &acc, smem, tid);
  #pragma unroll
  for (int v = 0; v < 4; ++v) {
    size_t idx = mo + (size_t)(i0 + orow + v) * 256 + (j0 + ocol);
    split_st(&Th[idx], &Tl[idx], acc[v]);
  }
}

// ---------------- Bjorck step 2: Wn = 1.5W - 0.5 W·T (+ Wn^T, + convert blocks) ----------------
__global__ __launch_bounds__(256) void bjorck_u_k(
    const u16* __restrict__ Wh, const u16* __restrict__ Wl,
    const u16* __restrict__ Th, const u16* __restrict__ Tl,
    u16* __restrict__ nWh, u16* __restrict__ nWl,
    u16* __restrict__ nWth, u16* __restrict__ nWtl,
    const float* __restrict__ x, u16* __restrict__ xb, int cvt_base) {
  __shared__ char smem[32768];
  int bx = blockIdx.x;
  if (bx >= 320) {
    int b = cvt_base + bx - 320;
    if (b < 32768) cvt_block(x, xb, b, smem);
    return;
  }
  int tid = threadIdx.x;
  int lane = tid & 63, wave = tid >> 6, qm = wave >> 1, qn = wave & 1;
  int orow = qm * 16 + ((lane >> 4) << 2);
  int ocol = qn * 16 + (lane & 15);
  int i0 = ((bx & 63) >> 3) * 32, j0 = (bx & 7) * 32;
  size_t mo = (size_t)(bx >> 6) * MSZ;
  f32x4 acc = {};
  gemm32_acc(Wh + mo, Wl + mo, i0, Th + mo, Tl + mo, j0, 256, &acc, smem, tid);
  #pragma unroll
  for (int v = 0; v < 4; ++v) {
    int r = i0 + orow + v, c = j0 + ocol;
    size_t idx = mo + (size_t)r * 256 + c;
    float wv = bf2f(Wh[idx]) + bf2f(Wl[idx]);
    float nv = 1.5f * wv - 0.5f * acc[v];
    split_st(&nWh[idx], &nWl[idx], nv);
    size_t idxT = mo + (size_t)c * 256 + r;
    split_st(&nWth[idxT], &nWtl[idxT], nv);
  }
}

// ---------------- PQ[t] = masked(O)·masked(O)^T (K=128) ----------------
__global__ __launch_bounds__(256) void pq_k(
    const u16* __restrict__ Wh, const u16* __restrict__ Wl,
    u16* __restrict__ PQh, u16* __restrict__ PQl) {
  GEMM_IDX
  int m4 = blockIdx.y;
  const u16* Oh = Wh + (size_t)(1 + m4) * MSZ;
  const u16* Ol = Wl + (size_t)(1 + m4) * MSZ;
  f32x4 acc = {};
  gemm32_acc(Oh, Ol, i0, Oh, Ol, j0, 128, &acc, smem, tid);
  #pragma unroll
  for (int v = 0; v < 4; ++v) {
    size_t idx = (size_t)m4 * MSZ + (size_t)(i0 + orow + v) * 256 + (j0 + ocol);
    split_st(&PQh[idx], &PQl[idx], acc[v]);
  }
}

// ---------------- fused: C1 = PQ0·PQ1, C2t = PQ3·PQ2, then block-orth members ----------------
__global__ __launch_bounds__(256) void c12b_k(
    const u16* __restrict__ PQh, const u16* __restrict__ PQl,
    u16* __restrict__ Ph, u16* __restrict__ Pl,
    u16* __restrict__ QTh, u16* __restrict__ QTl) {
  GEMM_IDX
  f32x4 a1 = {}, a2t = {};
  gemm32_acc(PQh, PQl, i0, PQh + MSZ, PQl + MSZ, j0, 256, &a1, smem, tid);
  gemm32_acc(PQh + 3 * MSZ, PQl + 3 * MSZ, i0, PQh + 2 * MSZ, PQl + 2 * MSZ, j0,
             256, &a2t, smem, tid);
  #pragma unroll
  for (int v = 0; v < 4; ++v) {
    int row = i0 + orow + v, col = j0 + ocol;
    size_t g = (size_t)row * 256 + col;
    float I = (row == col) ? 1.f : 0.f;
    float p0 = bf2f(PQh[g]) + bf2f(PQl[g]);
    float p1 = bf2f(PQh[MSZ + g]) + bf2f(PQl[MSZ + g]);
    float c1 = a1[v];
    split_st(&Ph[g],           &Pl[g],           c1);
    split_st(&Ph[MSZ + g],     &Pl[MSZ + g],     p0 - c1);
    split_st(&Ph[2*MSZ + g],   &Pl[2*MSZ + g],   p1 - c1);
    split_st(&Ph[3*MSZ + g],   &Pl[3*MSZ + g],   I - p0 - p1 + c1);
    float q0 = bf2f(PQh[2*MSZ + g]) + bf2f(PQl[2*MSZ + g]);
    float q1 = bf2f(PQh[3*MSZ + g]) + bf2f(PQl[3*MSZ + g]);
    float c2t = a2t[v];
    split_st(&QTh[g],          &QTl[g],          c2t);
    split_st(&QTh[MSZ + g],    &QTl[MSZ + g],    q0 - c2t);
    split_st(&QTh[2*MSZ + g],  &QTl[2*MSZ + g],  q1 - c2t);
    split_st(&QTh[3*MSZ + g],  &QTl[3*MSZ + g],  I - q0 - q1 + c2t);
  }
}

// ---------------- matrix_conv: R[ij] = sum_t P[tp]·Q[tq]; store R^T ----------------
__global__ __launch_bounds__(256) void mconv_k(
    const u16* __restrict__ Ph, const u16* __restrict__ Pl,
    const u16* __restrict__ QTh, const u16* __restrict__ QTl,
    u16* __restrict__ RTh, u16* __restrict__ RTl) {
  GEMM_IDX
  int ij = blockIdx.y;
  const int toff[10] = {0, 1, 3, 4, 6, 10, 12, 13, 15, 16};
  const int tp[16] = {0, 0, 1, 1, 0, 2, 0, 1, 2, 3, 1, 3, 2, 2, 3, 3};
  const int tq[16] = {0, 1, 0, 1, 2, 0, 3, 2, 1, 0, 3, 1, 2, 3, 2, 3};
  f32x4 acc = {};
  for (int t = toff[ij]; t < toff[ij + 1]; ++t) {
    gemm32_acc(Ph + (size_t)tp[t] * MSZ, Pl + (size_t)tp[t] * MSZ, i0,
               QTh + (size_t)tq[t] * MSZ, QTl + (size_t)tq[t] * MSZ, j0, 256, &acc, smem, tid);
  }
  #pragma unroll
  for (int v = 0; v < 4; ++v) {
    int r = i0 + orow + v, c = j0 + ocol;
    size_t idxT = (size_t)ij * MSZ + (size_t)c * 256 + r;  // R^T
    split_st(&RTh[idxT], &RTl[idxT], acc[v]);
  }
}

// ---------------- Wb: stage-major layout for the conv ----------------
// stage g = ct*18 + ij*2 + ks covers (cin tile ct*64+ks*32, tap ij), 16KB each.
// u16 index = g*8192 + (cout*4 + s)*8 + (cin&7), s = ((cin>>3)&3) ^ ((cout>>1)&3)
__global__ __launch_bounds__(256) void final_k(
    const u16* __restrict__ Hh, const u16* __restrict__ Hl,
    const u16* __restrict__ RTh, const u16* __restrict__ RTl,
    u16* __restrict__ WBQ) {
  GEMM_IDX
  int ij = blockIdx.y;
  f32x4 acc = {};
  gemm32_acc(Hh, Hl, i0, RTh + (size_t)ij * MSZ, RTl + (size_t)ij * MSZ, j0,
             256, &acc, smem, tid);
  #pragma unroll
  for (int v = 0; v < 4; ++v) {
    int r = i0 + orow + v, c = j0 + ocol;   // r = cin, c = cout
    int ct = r >> 6, ks = (r >> 5) & 1, jj = (r >> 3) & 3, e = r & 7;
    int s = jj ^ ((c >> 1) & 3);
    int g = ct * 18 + ij * 2 + ks;
    WBQ[(size_t)g * 8192 + (size_t)(c * 4 + s) * 8 + e] = f2bf(acc[v]);
  }
}

// ---------------- conv: implicit GEMM, MFMA bf16, gload_lds-staged ----------------
// grid 1024 (XCD-swizzled), 256 thr (4 waves, 2M x 2N). block = 2h x 64w x 256c.
// wave tile = 1h x 64w x 128 cout (acc[4][8]): 12 ds_read_b128 per 32 MFMA
// (6B/MFMA vs 8 at 64-cout waves) -> lower LDS-issue pressure per FLOP.
// LDS 64KB = sX 32KB (single buf) + sW 2x16KB dbuf -> 2 blocks/CU.
__global__ __launch_bounds__(256, 2) void conv_k(
    const u16* __restrict__ xb, const u16* __restrict__ Wb,
    const float* __restrict__ bias, float* __restrict__ out) {
  int braw = blockIdx.x;
  int L = (braw & 7) * 128 + (braw >> 3);   // bijective XCD swizzle (1024 % 8 == 0)
  int h2 = L & 31, n = L >> 5;
  int h0 = h2 * 2;
  int tid = threadIdx.x;
  int lane = tid & 63, wave = tid >> 6;     // 4 waves
  int wm = wave >> 1, wn = wave & 1;        // 2 M (h row) x 2 N (cout half)
  int fr = lane & 15, q = lane >> 4;

  __shared__ char smem[65536];
  char* sX = smem;                          // [r4][w64][128B cin] swizzled
  char* sW = smem + 32768;                  // [buf2][16KB stage]

  f32x4 acc[4][8] = {};

  auto issueX = [&](int ct) {
    #pragma unroll
    for (int i = 0; i < 8; ++i) {
      int d = (wave * 8 + i) * 64 + lane;   // chunk 0..2047
      int cb = (d & 7) * 16;
      int w = (d >> 3) & 63;
      int r = d >> 9;                       // 0..3 = rows h0-1..h0+2
      int hs = (h0 - 1 + r) & 63;
      const char* src = (const char*)xb + (((size_t)(n * 64 + hs) * 64 + w) << 9)
                        + ct * 128 + (cb ^ ((w & 7) << 4));
      gl16(src, sX + (wave * 8 + i) * 1024);
    }
  };
  auto issueW = [&](int g) {
    const char* base = (const char*)Wb + (size_t)g * 16384;
    char* dst = sW + (g & 1) * 16384;
    #pragma unroll
    for (int i = 0; i < 4; ++i) {
      int c = (wave * 4 + i) * 64 + lane;   // chunk 0..1023, pure linear
      gl16(base + c * 16, dst + (wave * 4 + i) * 1024);
    }
  };

  issueX(0);
  issueW(0);
  __syncthreads();

  for (int g = 0; g < 72; ++g) {
    int ct = g / 18, r18 = g % 18, tap = r18 >> 1, ks = r18 & 1;
    int kh = tap % 3, kw = tap / 3;         // tap == ij == kw*3+kh
    if (g + 1 < 72) issueW(g + 1);          // flies during compute + barrier
    const char* wb = sW + (g & 1) * 16384;
    __builtin_amdgcn_s_setprio(1);
    {
      bf16x8 af[4], bfr[8];
      #pragma unroll
      for (int fn = 0; fn < 8; ++fn) {
        int cl = wn * 128 + fn * 16 + fr;
        bfr[fn] = *(const bf16x8*)(wb + cl * 64 + ((q ^ ((cl >> 1) & 3)) << 4));
      }
      int kb2 = ks * 64 + q * 16;
      #pragma unroll
      for (int fm = 0; fm < 4; ++fm) {
        int wsrc = (fm * 16 + fr + kw + 63) & 63;
        af[fm] = *(const bf16x8*)(sX + ((wm + kh) * 64 + wsrc) * 128 + (kb2 ^ ((wsrc & 7) << 4)));
      }
      #pragma unroll
      for (int fm = 0; fm < 4; ++fm)
        #pragma unroll
        for (int fn = 0; fn < 8; ++fn)
          acc[fm][fn] = __builtin_amdgcn_mfma_f32_16x16x32_bf16(af[fm], bfr[fn], acc[fm][fn], 0, 0, 0);
    }
    __builtin_amdgcn_s_setprio(0);
    if (r18 == 17 && ct < 3) {
      __syncthreads();                      // all waves done with sX(ct); W(g+1) landed
      issueX(ct + 1);
      __syncthreads();                      // X landed (exposed; 3x per kernel)
    } else {
      __syncthreads();                      // W(g+1) landed + visible
    }
  }

  // epilogue: 2 rounds x 128 couts through LDS -> full 256B-row stores
  __syncthreads();
  float* sF = (float*)smem;                 // [cl128][h2][64w f32] swizzled, 64KB
  #pragma unroll
  for (int r = 0; r < 2; ++r) {
    if (wn == r) {
      #pragma unroll
      for (int fn = 0; fn < 8; ++fn) {
        int cl = fn * 16 + fr;              // 0..127
        float bv = bias[r * 128 + cl];
        #pragma unroll
        for (int fm = 0; fm < 4; ++fm) {
          f32x4 v = acc[fm][fn];
          v[0] += bv; v[1] += bv; v[2] += bv; v[3] += bv;
          *(f32x4*)((char*)sF + cl * 512 + wm * 256 +
                    (((unsigned)(fm * 64 + q * 16)) ^ ((unsigned)(cl & 7) << 4))) = v;
        }
      }
    }
    __syncthreads();
    #pragma unroll
    for (int p = 0; p < 16; ++p) {
      int e = tid + p * 256;                // 0..4095 f32x4 units
      int w4 = e & 15, hloc = (e >> 4) & 1, cl = e >> 5;   // cl 0..127
      f32x4 val = *(const f32x4*)((const char*)sF + cl * 512 + hloc * 256 +
                                  (((unsigned)(w4 * 16)) ^ ((unsigned)(cl & 7) << 4)));
      *(f32x4*)(out + (((size_t)n * 256 + r * 128 + cl) * 64 + (h0 + hloc)) * 64 + w4 * 4) = val;
    }
    if (r == 0) __syncthreads();            // WAR before round-1 LDS writes
  }
}

extern "C" void kernel_launch(void* const* d_in, const int* in_sizes, int n_in,
                              void* d_out, int out_size, void* d_ws, size_t ws_size,
                              hipStream_t stream) {
  const float* x = (const float*)d_in[0];
  const float* param = (const float*)d_in[1];
  const float* u0 = (const float*)d_in[2];
  const float* bias = (const float*)d_in[3];
  float* out = (float*)d_out;
  char* ws = (char*)d_ws;
  (void)in_sizes; (void)n_in; (void)out_size; (void)ws_size;

  float* B = (float*)(ws + O_AT);
  float* sval = (float*)(ws + O_SVAL);
  u16* xb = (u16*)(ws + O_XB);
  u16* W0h  = (u16*)(ws + O_W0);   u16* W0l  = W0h + 327680;
  u16* W0th = W0l + 327680;        u16* W0tl = W0th + 327680;
  u16* W1h  = (u16*)(ws + O_W1);   u16* W1l  = W1h + 327680;
  u16* W1th = W1l + 327680;        u16* W1tl = W1th + 327680;
  u16* Th = (u16*)(ws + O_TH);     u16* Tl = (u16*)(ws + O_TL);
  u16* PQh = (u16*)(ws + O_PQH);   u16* PQl = (u16*)(ws + O_PQL);
  u16* Ph = (u16*)(ws + O_PH);     u16* Pl = (u16*)(ws + O_PL);
  u16* QTh = (u16*)(ws + O_QTH);   u16* QTl = (u16*)(ws + O_QTL);
  u16* RTh = (u16*)(ws + O_RTH);   u16* RTl = (u16*)(ws + O_RTL);
  u16* WBQ = (u16*)(ws + O_WBQ);

  wtwA_k<<<dim3(64, 5), 256, 0, stream>>>(param, B);
  powerB_k<<<5, 1024, 0, stream>>>(param, B, u0, sval);
  scaleT_k<<<dim3(64, 5), 256, 0, stream>>>(param, sval, W0h, W0l, W0th, W0tl);

  u16 *cWh = W0h, *cWl = W0l, *cWth = W0th, *cWtl = W0tl;
  u16 *nWh = W1h, *nWl = W1l, *nWth = W1th, *nWtl = W1tl;
  for (int it = 0; it < 20; ++it) {
    bjorck_t_k<<<1140, 256, 0, stream>>>(cWth, cWtl, Th, Tl,
                                         x, xb, (2 * it) * 820);
    bjorck_u_k<<<1140, 256, 0, stream>>>(cWh, cWl, Th, Tl, nWh, nWl, nWth, nWtl,
                                         x, xb, (2 * it + 1) * 820);
    u16* t0;
    t0 = cWh; cWh = nWh; nWh = t0;
    t0 = cWl; cWl = nWl; nWl = t0;
    t0 = cWth; cWth = nWth; nWth = t0;
    t0 = cWtl; cWtl = nWtl; nWtl = t0;
  }
  // after 20 swaps cur == W0; W1 region is dead -> P/QT alias is safe

  pq_k<<<dim3(64, 4), 256, 0, stream>>>(cWh, cWl, PQh, PQl);
  c12b_k<<<64, 256, 0, stream>>>(PQh, PQl, Ph, Pl, QTh, QTl);
  mconv_k<<<dim3(64, 9), 256, 0, stream>>>(Ph, Pl, QTh, QTl, RTh, RTl);
  final_k<<<dim3(64, 9), 256, 0, stream>>>(cWh, cWl, RTh, RTl, WBQ);

  conv_k<<<1024, 256, 0, stream>>>(xb, WBQ, bias, out);
}

// Round 20
// 430.986 us; speedup vs baseline: 1.1025x; 1.0318x over previous
//
#include <hip/hip_runtime.h>
#include <stdint.h>

typedef unsigned short u16;
typedef unsigned short u16x4 __attribute__((ext_vector_type(4)));
typedef short bf16x8 __attribute__((ext_vector_type(8)));
typedef float f32x4 __attribute__((ext_vector_type(4)));

#define CDIM 256
#define MSZ 65536

// ---------------- ws layout (bytes) ----------------
constexpr size_t O_XB   = 0;                       // 64MB x bf16 NHWC
constexpr size_t O_AT   = 67108864;                // fp32 B=A^T A (dead after scaleT)
constexpr size_t O_PQH  = 67108864;                // alias B
constexpr size_t O_PQL  = O_PQH + 524288;
constexpr size_t O_SVAL = 68419584;
constexpr size_t O_W0   = 68419840;                // h,l,th,tl each 655360 B
constexpr size_t O_W1   = 71041280;
constexpr size_t O_PH   = 71041280;                // alias W1 (dead after bjorck)
constexpr size_t O_PL   = O_PH + 524288;
constexpr size_t O_QTH  = O_PL + 524288;
constexpr size_t O_QTL  = O_QTH + 524288;
constexpr size_t O_TH   = 73662720;
constexpr size_t O_TL   = O_TH + 655360;
constexpr size_t O_RTH  = 74973440;
constexpr size_t O_RTL  = O_RTH + 1179648;
constexpr size_t O_WBQ  = O_RTL + 1179648;         // 72 stages x 16KB = 1152KB

__device__ __forceinline__ u16 f2bf(float f) {
  union { float f; uint32_t u; } a; a.f = f;
  uint32_t u = a.u;
  uint32_t r = u + 0x7FFFu + ((u >> 16) & 1u);
  return (u16)(r >> 16);
}
__device__ __forceinline__ float bf2f(u16 u) {
  union { uint32_t u; float f; } a; a.u = ((uint32_t)u) << 16; return a.f;
}
__device__ __forceinline__ void split_st(u16* hi, u16* lo, float v) {
  u16 h = f2bf(v);
  *hi = h;
  *lo = f2bf(v - bf2f(h));
}
// async global->LDS, 16B per lane; l must be wave-uniform (dest = l + lane*16)
__device__ __forceinline__ void gl16(const void* g, void* l) {
  __builtin_amdgcn_global_load_lds(
      (const __attribute__((address_space(1))) void*)g,
      (__attribute__((address_space(3))) void*)l, 16, 0, 0);
}

// convert block body: x NCHW f32 -> xb NHWC bf16, one 32c x 32w tile
__device__ __forceinline__ void cvt_block(const float* __restrict__ x,
                                          u16* __restrict__ xb, int b, char* smem) {
  float (*t)[33] = (float(*)[33])smem;
  int ctile = b & 7, wtile = (b >> 3) & 1, h = (b >> 4) & 63, n = b >> 10;
  int c0 = ctile * 32, w0 = wtile * 32;
  int tid = threadIdx.x;
  #pragma unroll
  for (int p = 0; p < 4; p++) {
    int e = tid + p * 256; int cc = e >> 5, ww = e & 31;
    t[cc][ww] = x[(((size_t)n * 256 + c0 + cc) * 64 + h) * 64 + w0 + ww];
  }
  __syncthreads();
  {
    int ww = tid >> 3, c4 = (tid & 7) * 4;
    u16x4 v;
    #pragma unroll
    for (int j = 0; j < 4; ++j) v[j] = f2bf(t[c4 + j][ww]);
    *(u16x4*)&xb[(((size_t)n * 64 + h) * 64 + w0 + ww) * 256 + c0 + c4] = v;
  }
}

// ---------------- B = A^T A (fp32 VALU GEMM) ----------------
__global__ void wtwA_k(const float* __restrict__ W, float* __restrict__ T) {
  int m = blockIdx.y;
  int i0 = (blockIdx.x >> 3) * 32, j0 = (blockIdx.x & 7) * 32;
  const float* A = W + (size_t)m * MSZ;
  __shared__ float As[32][33], Bs[32][33];
  int tid = threadIdx.x, tx = tid & 15, ty = tid >> 4;
  float a00 = 0, a01 = 0, a10 = 0, a11 = 0;
  for (int kc = 0; kc < CDIM; kc += 32) {
    __syncthreads();
    for (int p = 0; p < 4; p++) {
      int e = tid + p * 256; int kk = e >> 5, cc = e & 31;
      As[kk][cc] = A[(kc + kk) * CDIM + i0 + cc];
      Bs[kk][cc] = A[(kc + kk) * CDIM + j0 + cc];
    }
    __syncthreads();
    #pragma unroll
    for (int kk = 0; kk < 32; kk++) {
      float av0 = As[kk][ty], av1 = As[kk][ty + 16];
      float bv0 = Bs[kk][tx], bv1 = Bs[kk][tx + 16];
      a00 += av0 * bv0; a01 += av0 * bv1; a10 += av1 * bv0; a11 += av1 * bv1;
    }
  }
  float* Tm = T + (size_t)m * MSZ;
  Tm[(i0 + ty) * CDIM + j0 + tx] = a00;
  Tm[(i0 + ty) * CDIM + j0 + tx + 16] = a01;
  Tm[(i0 + ty + 16) * CDIM + j0 + tx] = a10;
  Tm[(i0 + ty + 16) * CDIM + j0 + tx + 16] = a11;
}

// ---------------- power iteration via B = A^T A ----------------
__global__ __launch_bounds__(1024) void powerB_k(const float* __restrict__ A,
                                                 const float* __restrict__ B,
                                                 const float* __restrict__ u0,
                                                 float* __restrict__ sval) {
  int m = blockIdx.x;
  int tid = threadIdx.x;
  int t = tid & 255, s = tid >> 8;          // col t, row-slice s
  __shared__ float v[256], part[4][257];
  const float* Am = A + (size_t)m * MSZ;
  const float* Bm = B + (size_t)m * MSZ;
  float a = 0.f;
  #pragma unroll 16
  for (int i = 0; i < 64; ++i) a += Am[(s * 64 + i) * 256 + t] * u0[m * 256 + s * 64 + i];
  part[s][t] = a;
  __syncthreads();
  if (s == 0) v[t] = part[0][t] + part[1][t] + part[2][t] + part[3][t];
  __syncthreads();
  for (int it = 0; it < 9; ++it) {
    float b = 0.f;
    #pragma unroll 16
    for (int j = 0; j < 64; ++j) b += Bm[(s * 64 + j) * 256 + t] * v[s * 64 + j];
    part[s][t] = b;
    __syncthreads();
    if (s == 0) v[t] = part[0][t] + part[1][t] + part[2][t] + part[3][t];
    __syncthreads();
  }
  float b = 0.f;
  #pragma unroll 16
  for (int j = 0; j < 64; ++j) b += Bm[(s * 64 + j) * 256 + t] * v[s * 64 + j];
  part[s][t] = b;
  __syncthreads();
  if (s == 0) {
    float w = part[0][t] + part[1][t] + part[2][t] + part[3][t];
    float vv = v[t];
    float d1 = vv * w, d2 = vv * vv;
    for (int off = 32; off; off >>= 1) {
      d1 += __shfl_down(d1, off);
      d2 += __shfl_down(d2, off);
    }
    if ((t & 63) == 0) { part[1][t >> 6] = d1; part[2][t >> 6] = d2; }
  }
  __syncthreads();
  if (tid == 0) {
    float num = part[1][0] + part[1][1] + part[1][2] + part[1][3];
    float den = part[2][0] + part[2][1] + part[2][2] + part[2][3];
    sval[m] = sqrtf(num / den);
  }
}

// ---------------- scale + transpose + hi/lo split + T0 = B/sigma^2 ----------------
__global__ void scaleT_k(const float* __restrict__ param, const float* __restrict__ B,
                         const float* __restrict__ sval,
                         u16* __restrict__ Wh, u16* __restrict__ Wl,
                         u16* __restrict__ Wth, u16* __restrict__ Wtl,
                         u16* __restrict__ Th, u16* __restrict__ Tl) {
  __shared__ float tl[32][33];
  int m = blockIdx.y;
  int i0 = (blockIdx.x >> 3) * 32, j0 = (blockIdx.x & 7) * 32;
  int tid = threadIdx.x;
  float inv = 1.0f / sval[m];
  float inv2 = inv * inv;
  const float* Am = param + (size_t)m * MSZ;
  const float* Bm = B + (size_t)m * MSZ;
  size_t mo = (size_t)m * MSZ;
  for (int p = 0; p < 4; ++p) {
    int e = tid + p * 256; int ii = e >> 5, jj = e & 31;
    size_t rel = (size_t)(i0 + ii) * 256 + j0 + jj;
    float v = Am[rel] * inv;
    tl[ii][jj] = v;
    split_st(&Wh[mo + rel], &Wl[mo + rel], v);
    split_st(&Th[mo + rel], &Tl[mo + rel], Bm[rel] * inv2);   // T0 = B/sigma^2
  }
  __syncthreads();
  for (int p = 0; p < 4; ++p) {
    int e = tid + p * 256; int jj = e >> 5, ii = e & 31;
    float v = tl[ii][jj];
    size_t idxT = mo + (size_t)(j0 + jj) * 256 + i0 + ii;
    split_st(&Wth[idxT], &Wtl[idxT], v);
  }
}

// ---------------- hi/lo-split MFMA 32x32-tile GEMM: C += A·B^T ----------------
// FULL=true: 3-product hi/lo (precise). FULL=false: bf16-only (1 MFMA, 2 buffers).
template<bool FULL>
__device__ __forceinline__ void gemm32_acc(
    const u16* __restrict__ Ah, const u16* __restrict__ Al, int i0,
    const u16* __restrict__ Bh, const u16* __restrict__ Bl, int j0,
    int K, f32x4* acc, char* smem, int tid)
{
  int lane = tid & 63, wave = tid >> 6;
  int qm = wave >> 1, qn = wave & 1;
  int ra = qm * 16 + (lane & 15);
  int rb = qn * 16 + (lane & 15);
  int kb = (lane >> 4) * 16;
  for (int kc = 0; kc < K; kc += 128) {
    __syncthreads();
    if (FULL) {
      #pragma unroll
      for (int p = 0; p < 8; ++p) {
        int e = tid + p * 256;
        int bufi = e >> 9;               // 0:Ah 1:Al 2:Bh 3:Bl
        int r = (e >> 4) & 31;
        int cb = (e & 15) * 16;
        const u16* srcm = (bufi == 0) ? Ah : (bufi == 1) ? Al : (bufi == 2) ? Bh : Bl;
        int r0 = (bufi < 2) ? i0 : j0;
        const char* src = (const char*)srcm + ((size_t)(r0 + r) * 256 + kc) * 2 + cb;
        *(uint4*)(smem + bufi * 8192 + r * 256 + (cb ^ ((r & 7) << 4))) = *(const uint4*)src;
      }
    } else {
      #pragma unroll
      for (int p = 0; p < 4; ++p) {
        int e = tid + p * 256;
        int which = e >> 9;              // 0:Ah 1:Bh
        int r = (e >> 4) & 31;
        int cb = (e & 15) * 16;
        const u16* srcm = which ? Bh : Ah;
        int r0 = which ? j0 : i0;
        const char* src = (const char*)srcm + ((size_t)(r0 + r) * 256 + kc) * 2 + cb;
        *(uint4*)(smem + which * 16384 + r * 256 + (cb ^ ((r & 7) << 4))) = *(const uint4*)src;
      }
    }
    __syncthreads();
    #pragma unroll
    for (int ks = 0; ks < 4; ++ks) {
      int kbyte = ks * 64 + kb;
      int oa = ra * 256 + (kbyte ^ ((ra & 7) << 4));
      int ob = rb * 256 + (kbyte ^ ((rb & 7) << 4));
      bf16x8 ah = *(const bf16x8*)(smem + oa);
      bf16x8 bh = *(const bf16x8*)(smem + 16384 + ob);
      *acc = __builtin_amdgcn_mfma_f32_16x16x32_bf16(ah, bh, *acc, 0, 0, 0);
      if (FULL) {
        bf16x8 al = *(const bf16x8*)(smem + 8192 + oa);
        bf16x8 bl = *(const bf16x8*)(smem + 24576 + ob);
        *acc = __builtin_amdgcn_mfma_f32_16x16x32_bf16(ah, bl, *acc, 0, 0, 0);
        *acc = __builtin_amdgcn_mfma_f32_16x16x32_bf16(al, bh, *acc, 0, 0, 0);
      }
    }
  }
}

#define GEMM_IDX \
  int tid = threadIdx.x; \
  int lane = tid & 63, wave = tid >> 6, qm = wave >> 1, qn = wave & 1; \
  int orow = qm * 16 + ((lane >> 4) << 2); \
  int ocol = qn * 16 + (lane & 15); \
  int i0 = (blockIdx.x >> 3) * 32, j0 = (blockIdx.x & 7) * 32; \
  __shared__ char smem[32768];

// ---------------- Bjorck step 1: T = W^T W (+ piggybacked convert blocks) ----------------
template<bool FULL>
__global__ __launch_bounds__(256) void bjorck_t_k(
    const u16* __restrict__ Wth, const u16* __restrict__ Wtl,
    u16* __restrict__ Th, u16* __restrict__ Tl,
    const float* __restrict__ x, u16* __restrict__ xb, int cvt_base) {
  __shared__ char smem[32768];
  int bx = blockIdx.x;
  if (bx >= 320) {
    int b = cvt_base + bx - 320;
    if (b < 32768) cvt_block(x, xb, b, smem);
    return;
  }
  int tid = threadIdx.x;
  int lane = tid & 63, wave = tid >> 6, qm = wave >> 1, qn = wave & 1;
  int orow = qm * 16 + ((lane >> 4) << 2);
  int ocol = qn * 16 + (lane & 15);
  int i0 = ((bx & 63) >> 3) * 32, j0 = (bx & 7) * 32;
  size_t mo = (size_t)(bx >> 6) * MSZ;
  f32x4 acc = {};
  gemm32_acc<FULL>(Wth + mo, Wtl + mo, i0, Wth + mo, Wtl + mo, j0, 256, &acc, smem, tid);
  #pragma unroll
  for (int v = 0; v < 4; ++v) {
    size_t idx = mo + (size_t)(i0 + orow + v) * 256 + (j0 + ocol);
    split_st(&Th[idx], &Tl[idx], acc[v]);
  }
}

// ---------------- Bjorck step 2: Wn = 1.5W - 0.5 W·T (+ Wn^T, + convert blocks) ----------------
template<bool FULL>
__global__ __launch_bounds__(256) void bjorck_u_k(
    const u16* __restrict__ Wh, const u16* __restrict__ Wl,
    const u16* __restrict__ Th, const u16* __restrict__ Tl,
    u16* __restrict__ nWh, u16* __restrict__ nWl,
    u16* __restrict__ nWth, u16* __restrict__ nWtl,
    const float* __restrict__ x, u16* __restrict__ xb, int cvt_base) {
  __shared__ char smem[32768];
  int bx = blockIdx.x;
  if (bx >= 320) {
    int b = cvt_base + bx - 320;
    if (b < 32768) cvt_block(x, xb, b, smem);
    return;
  }
  int tid = threadIdx.x;
  int lane = tid & 63, wave = tid >> 6, qm = wave >> 1, qn = wave & 1;
  int orow = qm * 16 + ((lane >> 4) << 2);
  int ocol = qn * 16 + (lane & 15);
  int i0 = ((bx & 63) >> 3) * 32, j0 = (bx & 7) * 32;
  size_t mo = (size_t)(bx >> 6) * MSZ;
  f32x4 acc = {};
  gemm32_acc<FULL>(Wh + mo, Wl + mo, i0, Th + mo, Tl + mo, j0, 256, &acc, smem, tid);
  #pragma unroll
  for (int v = 0; v < 4; ++v) {
    int r = i0 + orow + v, c = j0 + ocol;
    size_t idx = mo + (size_t)r * 256 + c;
    float wv = bf2f(Wh[idx]) + bf2f(Wl[idx]);
    float nv = 1.5f * wv - 0.5f * acc[v];
    split_st(&nWh[idx], &nWl[idx], nv);
    size_t idxT = mo + (size_t)c * 256 + r;
    split_st(&nWth[idxT], &nWtl[idxT], nv);
  }
}

// ---------------- PQ[t] = masked(O)·masked(O)^T (K=128) ----------------
__global__ __launch_bounds__(256) void pq_k(
    const u16* __restrict__ Wh, const u16* __restrict__ Wl,
    u16* __restrict__ PQh, u16* __restrict__ PQl) {
  GEMM_IDX
  int m4 = blockIdx.y;
  const u16* Oh = Wh + (size_t)(1 + m4) * MSZ;
  const u16* Ol = Wl + (size_t)(1 + m4) * MSZ;
  f32x4 acc = {};
  gemm32_acc<true>(Oh, Ol, i0, Oh, Ol, j0, 128, &acc, smem, tid);
  #pragma unroll
  for (int v = 0; v < 4; ++v) {
    size_t idx = (size_t)m4 * MSZ + (size_t)(i0 + orow + v) * 256 + (j0 + ocol);
    split_st(&PQh[idx], &PQl[idx], acc[v]);
  }
}

// ---------------- fused: C1 = PQ0·PQ1, C2t = PQ3·PQ2, then block-orth members ----------------
__global__ __launch_bounds__(256) void c12b_k(
    const u16* __restrict__ PQh, const u16* __restrict__ PQl,
    u16* __restrict__ Ph, u16* __restrict__ Pl,
    u16* __restrict__ QTh, u16* __restrict__ QTl) {
  GEMM_IDX
  f32x4 a1 = {}, a2t = {};
  gemm32_acc<true>(PQh, PQl, i0, PQh + MSZ, PQl + MSZ, j0, 256, &a1, smem, tid);
  gemm32_acc<true>(PQh + 3 * MSZ, PQl + 3 * MSZ, i0, PQh + 2 * MSZ, PQl + 2 * MSZ, j0,
                   256, &a2t, smem, tid);
  #pragma unroll
  for (int v = 0; v < 4; ++v) {
    int row = i0 + orow + v, col = j0 + ocol;
    size_t g = (size_t)row * 256 + col;
    float I = (row == col) ? 1.f : 0.f;
    float p0 = bf2f(PQh[g]) + bf2f(PQl[g]);
    float p1 = bf2f(PQh[MSZ + g]) + bf2f(PQl[MSZ + g]);
    float c1 = a1[v];
    split_st(&Ph[g],           &Pl[g],           c1);
    split_st(&Ph[MSZ + g],     &Pl[MSZ + g],     p0 - c1);
    split_st(&Ph[2*MSZ + g],   &Pl[2*MSZ + g],   p1 - c1);
    split_st(&Ph[3*MSZ + g],   &Pl[3*MSZ + g],   I - p0 - p1 + c1);
    float q0 = bf2f(PQh[2*MSZ + g]) + bf2f(PQl[2*MSZ + g]);
    float q1 = bf2f(PQh[3*MSZ + g]) + bf2f(PQl[3*MSZ + g]);
    float c2t = a2t[v];
    split_st(&QTh[g],          &QTl[g],          c2t);
    split_st(&QTh[MSZ + g],    &QTl[MSZ + g],    q0 - c2t);
    split_st(&QTh[2*MSZ + g],  &QTl[2*MSZ + g],  q1 - c2t);
    split_st(&QTh[3*MSZ + g],  &QTl[3*MSZ + g],  I - q0 - q1 + c2t);
  }
}

// ---------------- matrix_conv: R[ij] = sum_t P[tp]·Q[tq]; store R^T ----------------
__global__ __launch_bounds__(256) void mconv_k(
    const u16* __restrict__ Ph, const u16* __restrict__ Pl,
    const u16* __restrict__ QTh, const u16* __restrict__ QTl,
    u16* __restrict__ RTh, u16* __restrict__ RTl) {
  GEMM_IDX
  int ij = blockIdx.y;
  const int toff[10] = {0, 1, 3, 4, 6, 10, 12, 13, 15, 16};
  const int tp[16] = {0, 0, 1, 1, 0, 2, 0, 1, 2, 3, 1, 3, 2, 2, 3, 3};
  const int tq[16] = {0, 1, 0, 1, 2, 0, 3, 2, 1, 0, 3, 1, 2, 3, 2, 3};
  f32x4 acc = {};
  for (int t = toff[ij]; t < toff[ij + 1]; ++t) {
    gemm32_acc<true>(Ph + (size_t)tp[t] * MSZ, Pl + (size_t)tp[t] * MSZ, i0,
                     QTh + (size_t)tq[t] * MSZ, QTl + (size_t)tq[t] * MSZ, j0, 256, &acc, smem, tid);
  }
  #pragma unroll
  for (int v = 0; v < 4; ++v) {
    int r = i0 + orow + v, c = j0 + ocol;
    size_t idxT = (size_t)ij * MSZ + (size_t)c * 256 + r;  // R^T
    split_st(&RTh[idxT], &RTl[idxT], acc[v]);
  }
}

// ---------------- Wb: stage-major layout for the conv ----------------
// stage g = ct*18 + ij*2 + ks covers (cin tile ct*64+ks*32, tap ij), 16KB each.
// u16 index = g*8192 + (cout*4 + s)*8 + (cin&7), s = ((cin>>3)&3) ^ ((cout>>1)&3)
__global__ __launch_bounds__(256) void final_k(
    const u16* __restrict__ Hh, const u16* __restrict__ Hl,
    const u16* __restrict__ RTh, const u16* __restrict__ RTl,
    u16* __restrict__ WBQ) {
  GEMM_IDX
  int ij = blockIdx.y;
  f32x4 acc = {};
  gemm32_acc<true>(Hh, Hl, i0, RTh + (size_t)ij * MSZ, RTl + (size_t)ij * MSZ, j0,
                   256, &acc, smem, tid);
  #pragma unroll
  for (int v = 0; v < 4; ++v) {
    int r = i0 + orow + v, c = j0 + ocol;   // r = cin, c = cout
    int ct = r >> 6, ks = (r >> 5) & 1, jj = (r >> 3) & 3, e = r & 7;
    int s = jj ^ ((c >> 1) & 3);
    int g = ct * 18 + ij * 2 + ks;
    WBQ[(size_t)g * 8192 + (size_t)(c * 4 + s) * 8 + e] = f2bf(acc[v]);
  }
}

// ---------------- conv: implicit GEMM, MFMA bf16, gload_lds-staged ----------------
// grid 1024 (XCD-swizzled), 256 thr (4 waves, 2M x 2N). block = 2h x 64w x 256c.
// wave tile = 1h x 64w x 128 cout (acc[4][8]). LDS 64KB = sX 32KB + sW 2x16KB.
__global__ __launch_bounds__(256, 2) void conv_k(
    const u16* __restrict__ xb, const u16* __restrict__ Wb,
    const float* __restrict__ bias, float* __restrict__ out) {
  int braw = blockIdx.x;
  int L = (braw & 7) * 128 + (braw >> 3);   // bijective XCD swizzle (1024 % 8 == 0)
  int h2 = L & 31, n = L >> 5;
  int h0 = h2 * 2;
  int tid = threadIdx.x;
  int lane = tid & 63, wave = tid >> 6;     // 4 waves
  int wm = wave >> 1, wn = wave & 1;        // 2 M (h row) x 2 N (cout half)
  int fr = lane & 15, q = lane >> 4;

  __shared__ char smem[65536];
  char* sX = smem;                          // [r4][w64][128B cin] swizzled
  char* sW = smem + 32768;                  // [buf2][16KB stage]

  f32x4 acc[4][8] = {};

  auto issueX = [&](int ct) {
    #pragma unroll
    for (int i = 0; i < 8; ++i) {
      int d = (wave * 8 + i) * 64 + lane;   // chunk 0..2047
      int cb = (d & 7) * 16;
      int w = (d >> 3) & 63;
      int r = d >> 9;                       // 0..3 = rows h0-1..h0+2
      int hs = (h0 - 1 + r) & 63;
      const char* src = (const char*)xb + (((size_t)(n * 64 + hs) * 64 + w) << 9)
                        + ct * 128 + (cb ^ ((w & 7) << 4));
      gl16(src, sX + (wave * 8 + i) * 1024);
    }
  };
  auto issueW = [&](int g) {
    const char* base = (const char*)Wb + (size_t)g * 16384;
    char* dst = sW + (g & 1) * 16384;
    #pragma unroll
    for (int i = 0; i < 4; ++i) {
      int c = (wave * 4 + i) * 64 + lane;   // chunk 0..1023, pure linear
      gl16(base + c * 16, dst + (wave * 4 + i) * 1024);
    }
  };

  issueX(0);
  issueW(0);
  __syncthreads();

  for (int g = 0; g < 72; ++g) {
    int ct = g / 18, r18 = g % 18, tap = r18 >> 1, ks = r18 & 1;
    int kh = tap % 3, kw = tap / 3;         // tap == ij == kw*3+kh
    if (g + 1 < 72) issueW(g + 1);          // flies during compute + barrier
    const char* wb = sW + (g & 1) * 16384;
    __builtin_amdgcn_s_setprio(1);
    {
      bf16x8 af[4], bfr[8];
      #pragma unroll
      for (int fn = 0; fn < 8; ++fn) {
        int cl = wn * 128 + fn * 16 + fr;
        bfr[fn] = *(const bf16x8*)(wb + cl * 64 + ((q ^ ((cl >> 1) & 3)) << 4));
      }
      int kb2 = ks * 64 + q * 16;
      #pragma unroll
      for (int fm = 0; fm < 4; ++fm) {
        int wsrc = (fm * 16 + fr + kw + 63) & 63;
        af[fm] = *(const bf16x8*)(sX + ((wm + kh) * 64 + wsrc) * 128 + (kb2 ^ ((wsrc & 7) << 4)));
      }
      #pragma unroll
      for (int fm = 0; fm < 4; ++fm)
        #pragma unroll
        for (int fn = 0; fn < 8; ++fn)
          acc[fm][fn] = __builtin_amdgcn_mfma_f32_16x16x32_bf16(af[fm], bfr[fn], acc[fm][fn], 0, 0, 0);
    }
    __builtin_amdgcn_s_setprio(0);
    if (r18 == 17 && ct < 3) {
      __syncthreads();                      // all waves done with sX(ct); W(g+1) landed
      issueX(ct + 1);
      __syncthreads();                      // X landed (exposed; 3x per kernel)
    } else {
      __syncthreads();                      // W(g+1) landed + visible
    }
  }

  // epilogue: 2 rounds x 128 couts through LDS -> full 256B-row stores
  __syncthreads();
  float* sF = (float*)smem;                 // [cl128][h2][64w f32] swizzled, 64KB
  #pragma unroll
  for (int r = 0; r < 2; ++r) {
    if (wn == r) {
      #pragma unroll
      for (int fn = 0; fn < 8; ++fn) {
        int cl = fn * 16 + fr;              // 0..127
        float bv = bias[r * 128 + cl];
        #pragma unroll
        for (int fm = 0; fm < 4; ++fm) {
          f32x4 v = acc[fm][fn];
          v[0] += bv; v[1] += bv; v[2] += bv; v[3] += bv;
          *(f32x4*)((char*)sF + cl * 512 + wm * 256 +
                    (((unsigned)(fm * 64 + q * 16)) ^ ((unsigned)(cl & 7) << 4))) = v;
        }
      }
    }
    __syncthreads();
    #pragma unroll
    for (int p = 0; p < 16; ++p) {
      int e = tid + p * 256;                // 0..4095 f32x4 units
      int w4 = e & 15, hloc = (e >> 4) & 1, cl = e >> 5;   // cl 0..127
      f32x4 val = *(const f32x4*)((const char*)sF + cl * 512 + hloc * 256 +
                                  (((unsigned)(w4 * 16)) ^ ((unsigned)(cl & 7) << 4)));
      *(f32x4*)(out + (((size_t)n * 256 + r * 128 + cl) * 64 + (h0 + hloc)) * 64 + w4 * 4) = val;
    }
    if (r == 0) __syncthreads();            // WAR before round-1 LDS writes
  }
}

extern "C" void kernel_launch(void* const* d_in, const int* in_sizes, int n_in,
                              void* d_out, int out_size, void* d_ws, size_t ws_size,
                              hipStream_t stream) {
  const float* x = (const float*)d_in[0];
  const float* param = (const float*)d_in[1];
  const float* u0 = (const float*)d_in[2];
  const float* bias = (const float*)d_in[3];
  float* out = (float*)d_out;
  char* ws = (char*)d_ws;
  (void)in_sizes; (void)n_in; (void)out_size; (void)ws_size;

  float* B = (float*)(ws + O_AT);
  float* sval = (float*)(ws + O_SVAL);
  u16* xb = (u16*)(ws + O_XB);
  u16* W0h  = (u16*)(ws + O_W0);   u16* W0l  = W0h + 327680;
  u16* W0th = W0l + 327680;        u16* W0tl = W0th + 327680;
  u16* W1h  = (u16*)(ws + O_W1);   u16* W1l  = W1h + 327680;
  u16* W1th = W1l + 327680;        u16* W1tl = W1th + 327680;
  u16* Th = (u16*)(ws + O_TH);     u16* Tl = (u16*)(ws + O_TL);
  u16* PQh = (u16*)(ws + O_PQH);   u16* PQl = (u16*)(ws + O_PQL);
  u16* Ph = (u16*)(ws + O_PH);     u16* Pl = (u16*)(ws + O_PL);
  u16* QTh = (u16*)(ws + O_QTH);   u16* QTl = (u16*)(ws + O_QTL);
  u16* RTh = (u16*)(ws + O_RTH);   u16* RTl = (u16*)(ws + O_RTL);
  u16* WBQ = (u16*)(ws + O_WBQ);

  wtwA_k<<<dim3(64, 5), 256, 0, stream>>>(param, B);
  powerB_k<<<5, 1024, 0, stream>>>(param, B, u0, sval);
  scaleT_k<<<dim3(64, 5), 256, 0, stream>>>(param, B, sval, W0h, W0l, W0th, W0tl, Th, Tl);

  u16 *cWh = W0h, *cWl = W0l, *cWth = W0th, *cWtl = W0tl;
  u16 *nWh = W1h, *nWl = W1l, *nWth = W1th, *nWtl = W1tl;
  int lc = 0;                                         // bjorck launch counter (39 total)
  const int CVT = 841;                                // 39*841 >= 32768
  for (int it = 0; it < 20; ++it) {
    if (it > 0) {                                     // it==0: T0 came from scaleT_k
      if (it < 14)
        bjorck_t_k<false><<<320 + CVT, 256, 0, stream>>>(cWth, cWtl, Th, Tl,
                                                         x, xb, (lc++) * CVT);
      else
        bjorck_t_k<true><<<320 + CVT, 256, 0, stream>>>(cWth, cWtl, Th, Tl,
                                                        x, xb, (lc++) * CVT);
    }
    if (it < 14)
      bjorck_u_k<false><<<320 + CVT, 256, 0, stream>>>(cWh, cWl, Th, Tl,
                                                       nWh, nWl, nWth, nWtl,
                                                       x, xb, (lc++) * CVT);
    else
      bjorck_u_k<true><<<320 + CVT, 256, 0, stream>>>(cWh, cWl, Th, Tl,
                                                      nWh, nWl, nWth, nWtl,
                                                      x, xb, (lc++) * CVT);
    u16* t0;
    t0 = cWh; cWh = nWh; nWh = t0;
    t0 = cWl; cWl = nWl; nWl = t0;
    t0 = cWth; cWth = nWth; nWth = t0;
    t0 = cWtl; cWtl = nWtl; nWtl = t0;
  }
  // after 20 swaps cur == W0; W1 region is dead -> P/QT alias is safe

  pq_k<<<dim3(64, 4), 256, 0, stream>>>(cWh, cWl, PQh, PQl);
  c12b_k<<<64, 256, 0, stream>>>(PQh, PQl, Ph, Pl, QTh, QTl);
  mconv_k<<<dim3(64, 9), 256, 0, stream>>>(Ph, Pl, QTh, QTl, RTh, RTl);
  final_k<<<dim3(64, 9), 256, 0, stream>>>(cWh, cWl, RTh, RTl, WBQ);

  conv_k<<<1024, 256, 0, stream>>>(xb, WBQ, bias, out);
}